// Round 1
// baseline (967.779 us; speedup 1.0000x reference)
//
#include <hip/hip_runtime.h>
#include <math.h>

// ---------------------------------------------------------------------------
// SNAT3: 4-layer GAT-like GNN on N=50000 nodes, E=800000 edges, HID=64.
// Pipeline per launch (everything rebuilt each call; ws is poisoned):
//   1. CSR build by dst (histogram -> scan -> scatter)
//   2. h = tanh(x @ W_embed)
//   3. 4x: feat = h @ Wg[l]; el/er; edge-softmax aggregate (one wave per node)
//      layer 0 writes mask (alpha >= 0.01), layers 1..3 apply it (-1e9 trick)
//   4. MLP head: relu(relu(relu([o0|o1|o2|o3] @ W0 + b0) @ W1 + b1) @ W2 + b2)
// ---------------------------------------------------------------------------

__global__ void k_zero_i32(int* __restrict__ p, int n) {
  int i = blockIdx.x * blockDim.x + threadIdx.x;
  if (i < n) p[i] = 0;
}

__global__ void k_hist(const int* __restrict__ dst, int* __restrict__ counts, int E) {
  int e = blockIdx.x * blockDim.x + threadIdx.x;
  if (e < E) atomicAdd(&counts[dst[e]], 1);
}

// single-block exclusive scan over counts -> row_ptr (and cursor copy)
__global__ __launch_bounds__(1024) void k_scan(const int* __restrict__ counts,
                                               int* __restrict__ row_ptr,
                                               int* __restrict__ cursor, int n) {
  __shared__ int sm[1024];
  __shared__ int s_carry;
  int tid = threadIdx.x;
  if (tid == 0) s_carry = 0;
  __syncthreads();
  for (int base = 0; base < n; base += 1024) {
    int i = base + tid;
    int v = (i < n) ? counts[i] : 0;
    sm[tid] = v;
    __syncthreads();
    for (int off = 1; off < 1024; off <<= 1) {
      int t = (tid >= off) ? sm[tid - off] : 0;
      __syncthreads();
      sm[tid] += t;
      __syncthreads();
    }
    int excl = s_carry + sm[tid] - v;
    if (i < n) { row_ptr[i] = excl; cursor[i] = excl; }
    __syncthreads();
    if (tid == 1023) s_carry += sm[1023];
    __syncthreads();
  }
  if (tid == 0) row_ptr[n] = s_carry;
}

__global__ void k_scatter(const int* __restrict__ src, const int* __restrict__ dst,
                          int* __restrict__ cursor, int* __restrict__ csr_src, int E) {
  int e = blockIdx.x * blockDim.x + threadIdx.x;
  if (e < E) {
    int pos = atomicAdd(&cursor[dst[e]], 1);
    csr_src[pos] = src[e];
  }
}

// h = tanh(x @ W_embed)   x:[N,128]  W:[128,64]  h:[N,64]
// one wave handles 4 nodes (register blocking amortizes the LDS W reads)
__global__ __launch_bounds__(256) void k_embed(const float* __restrict__ x,
                                               const float* __restrict__ W,
                                               float* __restrict__ h, int N) {
  __shared__ float sW[128 * 64];
  for (int i = threadIdx.x; i < 128 * 64; i += 256) sW[i] = W[i];
  __syncthreads();
  int wave = threadIdx.x >> 6, lane = threadIdx.x & 63;
  int q = blockIdx.x * 4 + wave;
  int n0 = q * 4;
  if (n0 >= N) return;
  int nl = N - 1;
  const float* x0 = x + (size_t)min(n0 + 0, nl) * 128;
  const float* x1 = x + (size_t)min(n0 + 1, nl) * 128;
  const float* x2 = x + (size_t)min(n0 + 2, nl) * 128;
  const float* x3 = x + (size_t)min(n0 + 3, nl) * 128;
  float a0 = 0.f, a1 = 0.f, a2 = 0.f, a3 = 0.f;
  for (int k = 0; k < 128; k++) {
    float w = sW[k * 64 + lane];
    a0 = fmaf(x0[k], w, a0);
    a1 = fmaf(x1[k], w, a1);
    a2 = fmaf(x2[k], w, a2);
    a3 = fmaf(x3[k], w, a3);
  }
  if (n0 + 0 < N) h[(size_t)(n0 + 0) * 64 + lane] = tanhf(a0);
  if (n0 + 1 < N) h[(size_t)(n0 + 1) * 64 + lane] = tanhf(a1);
  if (n0 + 2 < N) h[(size_t)(n0 + 2) * 64 + lane] = tanhf(a2);
  if (n0 + 3 < N) h[(size_t)(n0 + 3) * 64 + lane] = tanhf(a3);
}

// feat = hin @ Wg ; el = feat . al ; er = feat . ar    (per layer)
__global__ __launch_bounds__(256) void k_feat(const float* __restrict__ hin,
                                              const float* __restrict__ Wg,
                                              const float* __restrict__ al,
                                              const float* __restrict__ ar,
                                              float* __restrict__ feat,
                                              float* __restrict__ el,
                                              float* __restrict__ er, int N) {
  __shared__ float sW[64 * 64];
  __shared__ float sal[64], sar[64];
  for (int i = threadIdx.x; i < 64 * 64; i += 256) sW[i] = Wg[i];
  if (threadIdx.x < 64) { sal[threadIdx.x] = al[threadIdx.x]; sar[threadIdx.x] = ar[threadIdx.x]; }
  __syncthreads();
  int wave = threadIdx.x >> 6, lane = threadIdx.x & 63;
  int q = blockIdx.x * 4 + wave;
  int n0 = q * 4;
  if (n0 >= N) return;
  int nl = N - 1;
  const float* h0 = hin + (size_t)min(n0 + 0, nl) * 64;
  const float* h1 = hin + (size_t)min(n0 + 1, nl) * 64;
  const float* h2 = hin + (size_t)min(n0 + 2, nl) * 64;
  const float* h3 = hin + (size_t)min(n0 + 3, nl) * 64;
  float a0 = 0.f, a1 = 0.f, a2 = 0.f, a3 = 0.f;
  for (int k = 0; k < 64; k++) {
    float w = sW[k * 64 + lane];
    a0 = fmaf(h0[k], w, a0);
    a1 = fmaf(h1[k], w, a1);
    a2 = fmaf(h2[k], w, a2);
    a3 = fmaf(h3[k], w, a3);
  }
  float salv = sal[lane], sarv = sar[lane];
  float accs[4] = {a0, a1, a2, a3};
  #pragma unroll
  for (int i = 0; i < 4; i++) {
    int n = n0 + i;
    if (n < N) feat[(size_t)n * 64 + lane] = accs[i];
    float rl = accs[i] * salv, rr = accs[i] * sarv;
    #pragma unroll
    for (int off = 32; off; off >>= 1) {
      rl += __shfl_xor(rl, off, 64);
      rr += __shfl_xor(rr, off, 64);
    }
    if (lane == 0 && n < N) { el[n] = rl; er[n] = rr; }
  }
}

// edge-softmax + aggregate: one 64-lane wave per dst node, lane = feature.
__global__ __launch_bounds__(256) void k_aggr(const float* __restrict__ feat,
                                              const float* __restrict__ el,
                                              const float* __restrict__ er,
                                              const int* __restrict__ row_ptr,
                                              const int* __restrict__ csr_src,
                                              unsigned char* __restrict__ mask,
                                              int write_mask, int use_mask,
                                              float* __restrict__ hout, int N) {
  int wv = (int)((blockIdx.x * blockDim.x + threadIdx.x) >> 6);
  int lane = threadIdx.x & 63;
  if (wv >= N) return;
  int beg = row_ptr[wv], end = row_ptr[wv + 1];
  int deg = end - beg;
  float erv = er[wv];
  float m = -INFINITY, s = 0.f;
  int u0 = 0;
  float sc0 = -INFINITY;
  for (int base = beg; base < end; base += 64) {
    int k = base + lane;
    int u = 0;
    float sc = -INFINITY;
    if (k < end) {
      u = csr_src[k];
      float e0 = el[u] + erv;
      sc = (e0 >= 0.f) ? e0 : 0.2f * e0;           // leaky_relu(0.2)
      if (use_mask && mask[k] == 0) sc = -1e9f;    // pruned edge
    }
    if (base == beg) { u0 = u; sc0 = sc; }
    float cm = sc;
    #pragma unroll
    for (int off = 32; off; off >>= 1) cm = fmaxf(cm, __shfl_xor(cm, off, 64));
    float nm = fmaxf(m, cm);
    float t = (k < end) ? expf(sc - nm) : 0.f;
    #pragma unroll
    for (int off = 32; off; off >>= 1) t += __shfl_xor(t, off, 64);
    s = s * expf(m - nm) + t;
    m = nm;
  }
  float inv = 1.0f / fmaxf(s, 1e-9f);
  float acc = 0.f;
  if (deg <= 64) {
    // src indices and scores live in lane registers; broadcast with shfl
    for (int j = 0; j < deg; j++) {
      int u = __shfl(u0, j, 64);
      float sc = __shfl(sc0, j, 64);
      float p = expf(sc - m) * inv;                // alpha
      if (write_mask && lane == 0) mask[beg + j] = (p >= 0.01f) ? 1 : 0;
      acc = fmaf(p, feat[(size_t)u * 64 + lane], acc);
    }
  } else {
    for (int k = beg; k < end; k++) {
      int u = csr_src[k];
      float e0 = el[u] + erv;
      float sc = (e0 >= 0.f) ? e0 : 0.2f * e0;
      if (use_mask && mask[k] == 0) sc = -1e9f;
      float p = expf(sc - m) * inv;
      if (write_mask && lane == 0) mask[k] = (p >= 0.01f) ? 1 : 0;
      acc = fmaf(p, feat[(size_t)u * 64 + lane], acc);
    }
  }
  hout[(size_t)wv * 64 + lane] = (acc > 0.f) ? acc : expm1f(acc);  // elu
}

// MLP head. One wave handles 8 nodes. W0 staged in LDS (64KB), then LDS
// reused (after barrier) for W1 + per-wave t0 rows.
__global__ __launch_bounds__(256) void k_mlp(const float* __restrict__ o0,
                                             const float* __restrict__ o1,
                                             const float* __restrict__ o2,
                                             const float* __restrict__ o3,
                                             const float* __restrict__ W0,
                                             const float* __restrict__ b0,
                                             const float* __restrict__ W1,
                                             const float* __restrict__ b1,
                                             const float* __restrict__ W2,
                                             const float* __restrict__ b2,
                                             float* __restrict__ out, int N) {
  __shared__ float sm[256 * 64];  // 64 KB
  for (int i = threadIdx.x; i < 256 * 64; i += 256) sm[i] = W0[i];
  __syncthreads();
  int wave = threadIdx.x >> 6, lane = threadIdx.x & 63;
  int g = blockIdx.x * 4 + wave;
  int n0 = g * 8;
  int nl = N - 1;
  float acc[8];
  float b0v = b0[lane];
  #pragma unroll
  for (int i = 0; i < 8; i++) acc[i] = b0v;
  const float* segs[4] = {o0, o1, o2, o3};
  for (int sg = 0; sg < 4; sg++) {
    const float* sp = segs[sg];
    const float* wp = &sm[sg * 4096];
    for (int k = 0; k < 64; k++) {
      float w = wp[k * 64 + lane];
      #pragma unroll
      for (int i = 0; i < 8; i++) {
        int n = min(n0 + i, nl);
        acc[i] = fmaf(sp[(size_t)n * 64 + k], w, acc[i]);
      }
    }
  }
  __syncthreads();  // done with W0; reuse LDS
  for (int i = threadIdx.x; i < 64 * 64; i += 256) sm[i] = W1[i];
  #pragma unroll
  for (int i = 0; i < 8; i++) {
    float t = (acc[i] > 0.f) ? acc[i] : 0.f;  // relu layer 0
    sm[4096 + wave * 512 + i * 64 + lane] = t;
  }
  __syncthreads();
  float a1[8];
  float b1v = b1[lane];
  #pragma unroll
  for (int i = 0; i < 8; i++) a1[i] = b1v;
  for (int k = 0; k < 64; k++) {
    float w = sm[k * 64 + lane];
    #pragma unroll
    for (int i = 0; i < 8; i++) a1[i] = fmaf(sm[4096 + wave * 512 + i * 64 + k], w, a1[i]);
  }
  float w2 = W2[lane];
  float b2v = b2[0];
  #pragma unroll
  for (int i = 0; i < 8; i++) {
    float t = (a1[i] > 0.f) ? a1[i] : 0.f;    // relu layer 1
    float r = t * w2;
    #pragma unroll
    for (int off = 32; off; off >>= 1) r += __shfl_xor(r, off, 64);
    int n = n0 + i;
    if (lane == 0 && n < N) {
      float o = r + b2v;
      out[n] = (o > 0.f) ? o : 0.f;           // final relu
    }
  }
}

extern "C" void kernel_launch(void* const* d_in, const int* in_sizes, int n_in,
                              void* d_out, int out_size, void* d_ws, size_t ws_size,
                              hipStream_t stream) {
  const float* x       = (const float*)d_in[0];
  const int*   esrc    = (const int*)d_in[1];
  const int*   edst    = (const int*)d_in[2];
  const float* W_embed = (const float*)d_in[3];
  const float* W_gat   = (const float*)d_in[4];
  const float* a_l     = (const float*)d_in[5];
  const float* a_r     = (const float*)d_in[6];
  const float* W0      = (const float*)d_in[7];
  const float* b0      = (const float*)d_in[8];
  const float* W1      = (const float*)d_in[9];
  const float* b1      = (const float*)d_in[10];
  const float* W2      = (const float*)d_in[11];
  const float* b2      = (const float*)d_in[12];
  float* out = (float*)d_out;
  const int N = in_sizes[0] / 128;
  const int E = in_sizes[1];

  char* p = (char*)d_ws;
  auto alloc = [&](size_t bytes) -> char* {
    char* r = p;
    p += (bytes + 255) & ~(size_t)255;
    return r;
  };
  float* out0 = (float*)alloc((size_t)N * 64 * 4);
  float* out1 = (float*)alloc((size_t)N * 64 * 4);
  float* out2 = (float*)alloc((size_t)N * 64 * 4);
  float* out3 = (float*)alloc((size_t)N * 64 * 4);
  float* h    = out3;  // alias: h is dead before out3 is written (layer 3 aggr)
  float* feat = (float*)alloc((size_t)N * 64 * 4);
  float* el   = (float*)alloc((size_t)N * 4);
  float* er   = (float*)alloc((size_t)N * 4);
  int* counts  = (int*)alloc((size_t)N * 4);
  int* row_ptr = (int*)alloc((size_t)(N + 1) * 4);
  int* cursor  = (int*)alloc((size_t)N * 4);
  int* csr_src = (int*)alloc((size_t)E * 4);
  unsigned char* mask = (unsigned char*)alloc((size_t)E);

  // --- CSR build (dst-sorted) ---
  k_zero_i32<<<(N + 255) / 256, 256, 0, stream>>>(counts, N);
  k_hist<<<(E + 255) / 256, 256, 0, stream>>>(edst, counts, E);
  k_scan<<<1, 1024, 0, stream>>>(counts, row_ptr, cursor, N);
  k_scatter<<<(E + 255) / 256, 256, 0, stream>>>(esrc, edst, cursor, csr_src, E);

  // --- embed ---
  int quads = (N + 3) / 4;
  int qb = (quads + 3) / 4;
  k_embed<<<qb, 256, 0, stream>>>(x, W_embed, h, N);

  // --- 4 conv layers ---
  const float* hin = h;
  float* outs[4] = {out0, out1, out2, out3};
  for (int l = 0; l < 4; l++) {
    k_feat<<<qb, 256, 0, stream>>>(hin, W_gat + (size_t)l * 64 * 64,
                                   a_l + (size_t)l * 64, a_r + (size_t)l * 64,
                                   feat, el, er, N);
    k_aggr<<<(N + 3) / 4, 256, 0, stream>>>(feat, el, er, row_ptr, csr_src, mask,
                                            (l == 0) ? 1 : 0, (l > 0) ? 1 : 0,
                                            outs[l], N);
    hin = outs[l];
  }

  // --- MLP head ---
  int waves = (N + 7) / 8;
  int mblocks = (waves + 3) / 4;
  k_mlp<<<mblocks, 256, 0, stream>>>(out0, out1, out2, out3, W0, b0, W1, b1,
                                     W2, b2, out, N);
}

// Round 2
// 817.652 us; speedup vs baseline: 1.1836x; 1.1836x over previous
//
#include <hip/hip_runtime.h>
#include <math.h>

// ---------------------------------------------------------------------------
// SNAT3: 4-layer GAT-like GNN. N=50000, E=800000, HID=64, fp32.
//   1. CSR build by dst (histogram -> hierarchical scan -> scatter)
//   2. h = tanh(x @ W_embed)            [coalesced + LDS broadcast GEMM]
//   3. 4x: feat/el/er GEMM kernel; edge-softmax aggregate (1 wave per node)
//   4. MLP head relu(relu(relu(cat @ W0) @ W1) @ W2)
// Dense kernels: lane = out-feature, 8 nodes per wave; activation rows are
// loaded coalesced into a per-wave LDS buffer and re-read as wave-uniform
// ds_read_b128 broadcasts (no uniform global scalar loads in inner loops).
// ---------------------------------------------------------------------------

__global__ void k_zero_i32(int* __restrict__ p, int n) {
  int i = blockIdx.x * blockDim.x + threadIdx.x;
  if (i < n) p[i] = 0;
}

__global__ void k_hist(const int* __restrict__ dst, int* __restrict__ counts, int E) {
  int e = blockIdx.x * blockDim.x + threadIdx.x;
  if (e < E) atomicAdd(&counts[dst[e]], 1);
}

// ---- hierarchical scan: counts[n] -> row_ptr[n+1], cursor[n] ----
__global__ __launch_bounds__(1024) void k_bsum(const int* __restrict__ counts,
                                               int* __restrict__ bsum, int n) {
  __shared__ int wsum[16];
  int tid = threadIdx.x, lane = tid & 63, wid = tid >> 6;
  int i = blockIdx.x * 1024 + tid;
  int v = (i < n) ? counts[i] : 0;
  #pragma unroll
  for (int off = 32; off; off >>= 1) v += __shfl_xor(v, off, 64);
  if (lane == 0) wsum[wid] = v;
  __syncthreads();
  if (wid == 0) {
    int w = (lane < 16) ? wsum[lane] : 0;
    #pragma unroll
    for (int off = 8; off; off >>= 1) w += __shfl_xor(w, off, 64);
    if (lane == 0) bsum[blockIdx.x] = w;
  }
}

// single wave scans block sums -> bofs (exclusive); writes row_ptr[n]=total
__global__ __launch_bounds__(64) void k_bscan(const int* __restrict__ bsum,
                                              int* __restrict__ bofs,
                                              int* __restrict__ row_ptr,
                                              int nb, int n) {
  int lane = threadIdx.x;
  int carry = 0;
  for (int base = 0; base < nb; base += 64) {
    int idx = base + lane;
    int orig = (idx < nb) ? bsum[idx] : 0;
    int inc = orig;
    #pragma unroll
    for (int off = 1; off < 64; off <<= 1) {
      int t = __shfl_up(inc, off, 64);
      if (lane >= off) inc += t;
    }
    if (idx < nb) bofs[idx] = carry + inc - orig;
    carry += __shfl(inc, 63, 64);
  }
  if (lane == 0) row_ptr[n] = carry;
}

__global__ __launch_bounds__(1024) void k_scan3(const int* __restrict__ counts,
                                                const int* __restrict__ bofs,
                                                int* __restrict__ row_ptr,
                                                int* __restrict__ cursor, int n) {
  __shared__ int wsum[16];
  int tid = threadIdx.x, lane = tid & 63, wid = tid >> 6;
  int i = blockIdx.x * 1024 + tid;
  int v = (i < n) ? counts[i] : 0;
  int inc = v;
  #pragma unroll
  for (int off = 1; off < 64; off <<= 1) {
    int t = __shfl_up(inc, off, 64);
    if (lane >= off) inc += t;
  }
  if (lane == 63) wsum[wid] = inc;
  __syncthreads();
  if (wid == 0 && lane < 16) {
    int orig = wsum[lane];
    int w = orig;
    #pragma unroll
    for (int off = 1; off < 16; off <<= 1) {
      int t = __shfl_up(w, off, 64);
      if (lane >= off) w += t;
    }
    wsum[lane] = w - orig;  // exclusive wave offset
  }
  __syncthreads();
  int excl = bofs[blockIdx.x] + wsum[wid] + inc - v;
  if (i < n) { row_ptr[i] = excl; cursor[i] = excl; }
}

__global__ void k_scatter(const int* __restrict__ src, const int* __restrict__ dst,
                          int* __restrict__ cursor, int* __restrict__ csr_src, int E) {
  int e = blockIdx.x * blockDim.x + threadIdx.x;
  if (e < E) {
    int pos = atomicAdd(&cursor[dst[e]], 1);
    csr_src[pos] = src[e];
  }
}

// ---- h = tanh(x @ W_embed)   x:[N,128] W:[128,64] ----
__global__ __launch_bounds__(256) void k_embed(const float* __restrict__ x,
                                               const float* __restrict__ W,
                                               float* __restrict__ h, int N) {
  __shared__ __align__(16) float sW[128 * 64];       // 32 KB
  __shared__ __align__(16) float sF[4][8 * 128];     // 16 KB
  for (int i = threadIdx.x; i < 128 * 64; i += 256) sW[i] = W[i];
  __syncthreads();
  int wave = threadIdx.x >> 6, lane = threadIdx.x & 63;
  int n0 = (blockIdx.x * 4 + wave) * 8;
  if (n0 >= N) return;
  int nl = N - 1;
  float* sf = sF[wave];
  #pragma unroll
  for (int i = 0; i < 8; i++) {
    const float* xp = x + (size_t)min(n0 + i, nl) * 128;
    ((float2*)sf)[i * 64 + lane] = ((const float2*)xp)[lane];  // 512B coalesced
  }
  float acc[8];
  #pragma unroll
  for (int i = 0; i < 8; i++) acc[i] = 0.f;
  for (int k4 = 0; k4 < 32; k4++) {
    float w0 = sW[(k4 * 4 + 0) * 64 + lane];
    float w1 = sW[(k4 * 4 + 1) * 64 + lane];
    float w2 = sW[(k4 * 4 + 2) * 64 + lane];
    float w3 = sW[(k4 * 4 + 3) * 64 + lane];
    #pragma unroll
    for (int i = 0; i < 8; i++) {
      float4 f = *(const float4*)&sf[i * 128 + k4 * 4];  // uniform broadcast
      acc[i] = fmaf(f.x, w0, acc[i]);
      acc[i] = fmaf(f.y, w1, acc[i]);
      acc[i] = fmaf(f.z, w2, acc[i]);
      acc[i] = fmaf(f.w, w3, acc[i]);
    }
  }
  #pragma unroll
  for (int i = 0; i < 8; i++)
    if (n0 + i < N) h[(size_t)(n0 + i) * 64 + lane] = tanhf(acc[i]);
}

// ---- feat = hin @ Wg; el/er dot products ----
__global__ __launch_bounds__(256) void k_feat(const float* __restrict__ hin,
                                              const float* __restrict__ Wg,
                                              const float* __restrict__ al,
                                              const float* __restrict__ ar,
                                              float* __restrict__ feat,
                                              float* __restrict__ el,
                                              float* __restrict__ er, int N) {
  __shared__ __align__(16) float sW[64 * 64];     // 16 KB
  __shared__ __align__(16) float sF[4][8 * 64];   // 8 KB
  __shared__ float sal[64], sar[64];
  for (int i = threadIdx.x; i < 64 * 64; i += 256) sW[i] = Wg[i];
  if (threadIdx.x < 64) { sal[threadIdx.x] = al[threadIdx.x]; sar[threadIdx.x] = ar[threadIdx.x]; }
  __syncthreads();
  int wave = threadIdx.x >> 6, lane = threadIdx.x & 63;
  int n0 = (blockIdx.x * 4 + wave) * 8;
  if (n0 >= N) return;
  int nl = N - 1;
  float* sf = sF[wave];
  #pragma unroll
  for (int i = 0; i < 8; i++)
    sf[i * 64 + lane] = hin[(size_t)min(n0 + i, nl) * 64 + lane];
  float acc[8];
  #pragma unroll
  for (int i = 0; i < 8; i++) acc[i] = 0.f;
  for (int k4 = 0; k4 < 16; k4++) {
    float w0 = sW[(k4 * 4 + 0) * 64 + lane];
    float w1 = sW[(k4 * 4 + 1) * 64 + lane];
    float w2 = sW[(k4 * 4 + 2) * 64 + lane];
    float w3 = sW[(k4 * 4 + 3) * 64 + lane];
    #pragma unroll
    for (int i = 0; i < 8; i++) {
      float4 f = *(const float4*)&sf[i * 64 + k4 * 4];
      acc[i] = fmaf(f.x, w0, acc[i]);
      acc[i] = fmaf(f.y, w1, acc[i]);
      acc[i] = fmaf(f.z, w2, acc[i]);
      acc[i] = fmaf(f.w, w3, acc[i]);
    }
  }
  float salv = sal[lane], sarv = sar[lane];
  #pragma unroll
  for (int i = 0; i < 8; i++) {
    int n = n0 + i;
    if (n < N) feat[(size_t)n * 64 + lane] = acc[i];
    float rl = acc[i] * salv, rr = acc[i] * sarv;
    #pragma unroll
    for (int off = 32; off; off >>= 1) {
      rl += __shfl_xor(rl, off, 64);
      rr += __shfl_xor(rr, off, 64);
    }
    if (lane == 0 && n < N) { el[n] = rl; er[n] = rr; }
  }
}

// ---- edge softmax + aggregate: one wave per dst node, lane = feature ----
__global__ __launch_bounds__(256) void k_aggr(const float* __restrict__ feat,
                                              const float* __restrict__ el,
                                              const float* __restrict__ er,
                                              const int* __restrict__ row_ptr,
                                              const int* __restrict__ csr_src,
                                              unsigned char* __restrict__ mask,
                                              int write_mask, int use_mask,
                                              float* __restrict__ hout, int N) {
  int wv = (int)((blockIdx.x * blockDim.x + threadIdx.x) >> 6);
  int lane = threadIdx.x & 63;
  if (wv >= N) return;
  int beg = row_ptr[wv], end = row_ptr[wv + 1];
  int deg = end - beg;
  float erv = er[wv];
  float acc0 = 0.f, acc1 = 0.f, acc2 = 0.f, acc3 = 0.f;
  if (deg <= 64) {
    int k = beg + lane;
    bool have = (lane < deg);
    int u = have ? csr_src[k] : 0;
    float sc = -INFINITY;
    if (have) {
      float e0 = el[u] + erv;
      sc = (e0 >= 0.f) ? e0 : 0.2f * e0;              // leaky_relu(0.2)
      if (use_mask && mask[k] == 0) sc = -1e9f;       // pruned
    }
    float m = sc;
    #pragma unroll
    for (int off = 32; off; off >>= 1) m = fmaxf(m, __shfl_xor(m, off, 64));
    float pl = have ? expf(sc - m) : 0.f;             // one expf per lane
    float s = pl;
    #pragma unroll
    for (int off = 32; off; off >>= 1) s += __shfl_xor(s, off, 64);
    pl *= 1.0f / fmaxf(s, 1e-9f);                     // alpha for this lane's edge
    if (write_mask && have) mask[k] = (pl >= 0.01f) ? 1 : 0;   // coalesced store
    int j = 0;
    for (; j + 4 <= deg; j += 4) {
      int u0 = __shfl(u, j + 0, 64), u1 = __shfl(u, j + 1, 64);
      int u2 = __shfl(u, j + 2, 64), u3 = __shfl(u, j + 3, 64);
      float p0 = __shfl(pl, j + 0, 64), p1 = __shfl(pl, j + 1, 64);
      float p2 = __shfl(pl, j + 2, 64), p3 = __shfl(pl, j + 3, 64);
      acc0 = fmaf(p0, feat[(size_t)u0 * 64 + lane], acc0);
      acc1 = fmaf(p1, feat[(size_t)u1 * 64 + lane], acc1);
      acc2 = fmaf(p2, feat[(size_t)u2 * 64 + lane], acc2);
      acc3 = fmaf(p3, feat[(size_t)u3 * 64 + lane], acc3);
    }
    for (; j < deg; j++) {
      int u0 = __shfl(u, j, 64);
      float p0 = __shfl(pl, j, 64);
      acc0 = fmaf(p0, feat[(size_t)u0 * 64 + lane], acc0);
    }
  } else {
    // generic fallback (deg > 64): streaming two-pass
    float m = -INFINITY, s = 0.f;
    for (int base = beg; base < end; base += 64) {
      int k = base + lane;
      float sc = -INFINITY;
      if (k < end) {
        int u = csr_src[k];
        float e0 = el[u] + erv;
        sc = (e0 >= 0.f) ? e0 : 0.2f * e0;
        if (use_mask && mask[k] == 0) sc = -1e9f;
      }
      float cm = sc;
      #pragma unroll
      for (int off = 32; off; off >>= 1) cm = fmaxf(cm, __shfl_xor(cm, off, 64));
      float nm = fmaxf(m, cm);
      float t = (k < end) ? expf(sc - nm) : 0.f;
      #pragma unroll
      for (int off = 32; off; off >>= 1) t += __shfl_xor(t, off, 64);
      s = s * expf(m - nm) + t;
      m = nm;
    }
    float inv = 1.0f / fmaxf(s, 1e-9f);
    for (int base = beg; base < end; base += 64) {
      int k = base + lane;
      int u = 0;
      float pl = 0.f;
      if (k < end) {
        u = csr_src[k];
        float e0 = el[u] + erv;
        float sc = (e0 >= 0.f) ? e0 : 0.2f * e0;
        if (use_mask && mask[k] == 0) sc = -1e9f;
        pl = expf(sc - m) * inv;
        if (write_mask) mask[k] = (pl >= 0.01f) ? 1 : 0;
      }
      int cnt = min(64, end - base);
      for (int j = 0; j < cnt; j++) {
        int u0 = __shfl(u, j, 64);
        float p0 = __shfl(pl, j, 64);
        acc0 = fmaf(p0, feat[(size_t)u0 * 64 + lane], acc0);
      }
    }
  }
  float acc = (acc0 + acc1) + (acc2 + acc3);
  hout[(size_t)wv * 64 + lane] = (acc > 0.f) ? acc : expm1f(acc);  // elu
}

// ---- MLP head ----
__global__ __launch_bounds__(256) void k_mlp(const float* __restrict__ o0,
                                             const float* __restrict__ o1,
                                             const float* __restrict__ o2,
                                             const float* __restrict__ o3,
                                             const float* __restrict__ W0,
                                             const float* __restrict__ b0,
                                             const float* __restrict__ W1,
                                             const float* __restrict__ b1,
                                             const float* __restrict__ W2,
                                             const float* __restrict__ b2,
                                             float* __restrict__ out, int N) {
  __shared__ __align__(16) float sW[256 * 64];    // 64 KB (W0, then W1 reuses front)
  __shared__ __align__(16) float sF[4][8 * 64];   // 8 KB per-wave stage
  for (int i = threadIdx.x; i < 256 * 64; i += 256) sW[i] = W0[i];
  __syncthreads();
  int wave = threadIdx.x >> 6, lane = threadIdx.x & 63;
  int n0 = (blockIdx.x * 4 + wave) * 8;
  int nl = N - 1;
  float* sf = sF[wave];
  float acc[8];
  float b0v = b0[lane];
  #pragma unroll
  for (int i = 0; i < 8; i++) acc[i] = b0v;
  const float* segs[4] = {o0, o1, o2, o3};
  for (int sg = 0; sg < 4; sg++) {
    const float* sp = segs[sg];
    #pragma unroll
    for (int i = 0; i < 8; i++)
      sf[i * 64 + lane] = sp[(size_t)min(n0 + i, nl) * 64 + lane];
    const float* wp = &sW[sg * 4096];
    for (int k4 = 0; k4 < 16; k4++) {
      float w0 = wp[(k4 * 4 + 0) * 64 + lane];
      float w1 = wp[(k4 * 4 + 1) * 64 + lane];
      float w2 = wp[(k4 * 4 + 2) * 64 + lane];
      float w3 = wp[(k4 * 4 + 3) * 64 + lane];
      #pragma unroll
      for (int i = 0; i < 8; i++) {
        float4 f = *(const float4*)&sf[i * 64 + k4 * 4];
        acc[i] = fmaf(f.x, w0, acc[i]);
        acc[i] = fmaf(f.y, w1, acc[i]);
        acc[i] = fmaf(f.z, w2, acc[i]);
        acc[i] = fmaf(f.w, w3, acc[i]);
      }
    }
  }
  __syncthreads();  // done reading W0 + own stage
  for (int i = threadIdx.x; i < 64 * 64; i += 256) sW[i] = W1[i];
  #pragma unroll
  for (int i = 0; i < 8; i++)
    sf[i * 64 + lane] = (acc[i] > 0.f) ? acc[i] : 0.f;   // relu
  __syncthreads();
  float a1[8];
  float b1v = b1[lane];
  #pragma unroll
  for (int i = 0; i < 8; i++) a1[i] = b1v;
  for (int k4 = 0; k4 < 16; k4++) {
    float w0 = sW[(k4 * 4 + 0) * 64 + lane];
    float w1 = sW[(k4 * 4 + 1) * 64 + lane];
    float w2 = sW[(k4 * 4 + 2) * 64 + lane];
    float w3 = sW[(k4 * 4 + 3) * 64 + lane];
    #pragma unroll
    for (int i = 0; i < 8; i++) {
      float4 f = *(const float4*)&sf[i * 64 + k4 * 4];
      a1[i] = fmaf(f.x, w0, a1[i]);
      a1[i] = fmaf(f.y, w1, a1[i]);
      a1[i] = fmaf(f.z, w2, a1[i]);
      a1[i] = fmaf(f.w, w3, a1[i]);
    }
  }
  float w2v = W2[lane];
  float b2v = b2[0];
  #pragma unroll
  for (int i = 0; i < 8; i++) {
    float t = (a1[i] > 0.f) ? a1[i] : 0.f;
    float r = t * w2v;
    #pragma unroll
    for (int off = 32; off; off >>= 1) r += __shfl_xor(r, off, 64);
    int n = n0 + i;
    if (lane == 0 && n < N) {
      float o = r + b2v;
      out[n] = (o > 0.f) ? o : 0.f;
    }
  }
}

extern "C" void kernel_launch(void* const* d_in, const int* in_sizes, int n_in,
                              void* d_out, int out_size, void* d_ws, size_t ws_size,
                              hipStream_t stream) {
  const float* x       = (const float*)d_in[0];
  const int*   esrc    = (const int*)d_in[1];
  const int*   edst    = (const int*)d_in[2];
  const float* W_embed = (const float*)d_in[3];
  const float* W_gat   = (const float*)d_in[4];
  const float* a_l     = (const float*)d_in[5];
  const float* a_r     = (const float*)d_in[6];
  const float* W0      = (const float*)d_in[7];
  const float* b0      = (const float*)d_in[8];
  const float* W1      = (const float*)d_in[9];
  const float* b1      = (const float*)d_in[10];
  const float* W2      = (const float*)d_in[11];
  const float* b2      = (const float*)d_in[12];
  float* out = (float*)d_out;
  const int N = in_sizes[0] / 128;
  const int E = in_sizes[1];

  char* p = (char*)d_ws;
  auto alloc = [&](size_t bytes) -> char* {
    char* r = p;
    p += (bytes + 255) & ~(size_t)255;
    return r;
  };
  float* out0 = (float*)alloc((size_t)N * 64 * 4);
  float* out1 = (float*)alloc((size_t)N * 64 * 4);
  float* out2 = (float*)alloc((size_t)N * 64 * 4);
  float* out3 = (float*)alloc((size_t)N * 64 * 4);
  float* h    = out3;  // alias: h dead before out3 written
  float* feat = (float*)alloc((size_t)N * 64 * 4);
  float* el   = (float*)alloc((size_t)N * 4);
  float* er   = (float*)alloc((size_t)N * 4);
  int* counts  = (int*)alloc((size_t)N * 4);
  int* row_ptr = (int*)alloc((size_t)(N + 1) * 4);
  int* cursor  = (int*)alloc((size_t)N * 4);
  int* csr_src = (int*)alloc((size_t)E * 4);
  unsigned char* mask = (unsigned char*)alloc((size_t)E);
  int nb = (N + 1023) / 1024;
  int* bsum = (int*)alloc((size_t)nb * 4);
  int* bofs = (int*)alloc((size_t)nb * 4);

  // --- CSR build (dst-sorted) ---
  k_zero_i32<<<(N + 255) / 256, 256, 0, stream>>>(counts, N);
  k_hist<<<(E + 255) / 256, 256, 0, stream>>>(edst, counts, E);
  k_bsum<<<nb, 1024, 0, stream>>>(counts, bsum, N);
  k_bscan<<<1, 64, 0, stream>>>(bsum, bofs, row_ptr, nb, N);
  k_scan3<<<nb, 1024, 0, stream>>>(counts, bofs, row_ptr, cursor, N);
  k_scatter<<<(E + 255) / 256, 256, 0, stream>>>(esrc, edst, cursor, csr_src, E);

  // --- embed ---
  int groups = (N + 7) / 8;
  int gb = (groups + 3) / 4;
  k_embed<<<gb, 256, 0, stream>>>(x, W_embed, h, N);

  // --- 4 conv layers ---
  const float* hin = h;
  float* outs[4] = {out0, out1, out2, out3};
  for (int l = 0; l < 4; l++) {
    k_feat<<<gb, 256, 0, stream>>>(hin, W_gat + (size_t)l * 64 * 64,
                                   a_l + (size_t)l * 64, a_r + (size_t)l * 64,
                                   feat, el, er, N);
    k_aggr<<<(N + 3) / 4, 256, 0, stream>>>(feat, el, er, row_ptr, csr_src, mask,
                                            (l == 0) ? 1 : 0, (l > 0) ? 1 : 0,
                                            outs[l], N);
    hin = outs[l];
  }

  // --- MLP head ---
  k_mlp<<<gb, 256, 0, stream>>>(out0, out1, out2, out3, W0, b0, W1, b1,
                                W2, b2, out, N);
}

// Round 3
// 657.250 us; speedup vs baseline: 1.4725x; 1.2440x over previous
//
#include <hip/hip_runtime.h>
#include <math.h>

// ---------------------------------------------------------------------------
// SNAT3: 4-layer GAT-like GNN. N=50000, E=800000, HID=64, fp32.
//   1. CSR build by dst (histogram -> hierarchical scan -> scatter)
//   2. h = tanh(x @ W_embed)
//   3. 4x: feat/el/er GEMM; edge-softmax aggregate (1 wave per dst node)
//   4. MLP head relu(relu(relu(cat @ W0) @ W1) @ W2)
// Dense GEMMs: lane = out-feature, 8 nodes/wave. Weights are per-lane
// coalesced GLOBAL loads (L1/L2-resident); activations are wave-uniform
// float4 GLOBAL loads (scalar/broadcast path). No LDS in the inner loops
// (LDS pipe is shared by 4 SIMDs -> was the structural limiter), and
// #pragma unroll 2 keeps VGPRs < 128 (R2's 256-VGPR spill disaster).
// ---------------------------------------------------------------------------

__global__ void k_zero_i32(int* __restrict__ p, int n) {
  int i = blockIdx.x * blockDim.x + threadIdx.x;
  if (i < n) p[i] = 0;
}

__global__ void k_hist(const int* __restrict__ dst, int* __restrict__ counts, int E) {
  int e = blockIdx.x * blockDim.x + threadIdx.x;
  if (e < E) atomicAdd(&counts[dst[e]], 1);
}

__global__ __launch_bounds__(1024) void k_bsum(const int* __restrict__ counts,
                                               int* __restrict__ bsum, int n) {
  __shared__ int wsum[16];
  int tid = threadIdx.x, lane = tid & 63, wid = tid >> 6;
  int i = blockIdx.x * 1024 + tid;
  int v = (i < n) ? counts[i] : 0;
  #pragma unroll
  for (int off = 32; off; off >>= 1) v += __shfl_xor(v, off, 64);
  if (lane == 0) wsum[wid] = v;
  __syncthreads();
  if (wid == 0) {
    int w = (lane < 16) ? wsum[lane] : 0;
    #pragma unroll
    for (int off = 8; off; off >>= 1) w += __shfl_xor(w, off, 64);
    if (lane == 0) bsum[blockIdx.x] = w;
  }
}

__global__ __launch_bounds__(64) void k_bscan(const int* __restrict__ bsum,
                                              int* __restrict__ bofs,
                                              int* __restrict__ row_ptr,
                                              int nb, int n) {
  int lane = threadIdx.x;
  int carry = 0;
  for (int base = 0; base < nb; base += 64) {
    int idx = base + lane;
    int orig = (idx < nb) ? bsum[idx] : 0;
    int inc = orig;
    #pragma unroll
    for (int off = 1; off < 64; off <<= 1) {
      int t = __shfl_up(inc, off, 64);
      if (lane >= off) inc += t;
    }
    if (idx < nb) bofs[idx] = carry + inc - orig;
    carry += __shfl(inc, 63, 64);
  }
  if (lane == 0) row_ptr[n] = carry;
}

__global__ __launch_bounds__(1024) void k_scan3(const int* __restrict__ counts,
                                                const int* __restrict__ bofs,
                                                int* __restrict__ row_ptr,
                                                int* __restrict__ cursor, int n) {
  __shared__ int wsum[16];
  int tid = threadIdx.x, lane = tid & 63, wid = tid >> 6;
  int i = blockIdx.x * 1024 + tid;
  int v = (i < n) ? counts[i] : 0;
  int inc = v;
  #pragma unroll
  for (int off = 1; off < 64; off <<= 1) {
    int t = __shfl_up(inc, off, 64);
    if (lane >= off) inc += t;
  }
  if (lane == 63) wsum[wid] = inc;
  __syncthreads();
  if (wid == 0 && lane < 16) {
    int orig = wsum[lane];
    int w = orig;
    #pragma unroll
    for (int off = 1; off < 16; off <<= 1) {
      int t = __shfl_up(w, off, 64);
      if (lane >= off) w += t;
    }
    wsum[lane] = w - orig;
  }
  __syncthreads();
  int excl = bofs[blockIdx.x] + wsum[wid] + inc - v;
  if (i < n) { row_ptr[i] = excl; cursor[i] = excl; }
}

__global__ void k_scatter(const int* __restrict__ src, const int* __restrict__ dst,
                          int* __restrict__ cursor, int* __restrict__ csr_src, int E) {
  int e = blockIdx.x * blockDim.x + threadIdx.x;
  if (e < E) {
    int pos = atomicAdd(&cursor[dst[e]], 1);
    csr_src[pos] = src[e];
  }
}

// ---- h = tanh(x @ W_embed)   x:[N,128] W:[128,64] ----
__global__ __launch_bounds__(256) void k_embed(const float* __restrict__ x,
                                               const float* __restrict__ W,
                                               float* __restrict__ h, int N) {
  int wave = threadIdx.x >> 6, lane = threadIdx.x & 63;
  int n0 = (blockIdx.x * 4 + wave) * 8;
  if (n0 >= N) return;
  int nl = N - 1;
  const float* base[8];
  #pragma unroll
  for (int i = 0; i < 8; i++) base[i] = x + (size_t)min(n0 + i, nl) * 128;
  float acc[8];
  #pragma unroll
  for (int i = 0; i < 8; i++) acc[i] = 0.f;
  #pragma unroll 2
  for (int k4 = 0; k4 < 32; k4++) {
    float w0 = W[(k4 * 4 + 0) * 64 + lane];
    float w1 = W[(k4 * 4 + 1) * 64 + lane];
    float w2 = W[(k4 * 4 + 2) * 64 + lane];
    float w3 = W[(k4 * 4 + 3) * 64 + lane];
    #pragma unroll
    for (int i = 0; i < 8; i++) {
      float4 a = *(const float4*)(base[i] + k4 * 4);  // wave-uniform broadcast
      acc[i] = fmaf(a.x, w0, acc[i]);
      acc[i] = fmaf(a.y, w1, acc[i]);
      acc[i] = fmaf(a.z, w2, acc[i]);
      acc[i] = fmaf(a.w, w3, acc[i]);
    }
  }
  #pragma unroll
  for (int i = 0; i < 8; i++)
    if (n0 + i < N) h[(size_t)(n0 + i) * 64 + lane] = tanhf(acc[i]);
}

// ---- feat = hin @ Wg; el/er dot products ----
__global__ __launch_bounds__(256) void k_feat(const float* __restrict__ hin,
                                              const float* __restrict__ Wg,
                                              const float* __restrict__ al,
                                              const float* __restrict__ ar,
                                              float* __restrict__ feat,
                                              float* __restrict__ el,
                                              float* __restrict__ er, int N) {
  int wave = threadIdx.x >> 6, lane = threadIdx.x & 63;
  int n0 = (blockIdx.x * 4 + wave) * 8;
  if (n0 >= N) return;
  int nl = N - 1;
  const float* base[8];
  #pragma unroll
  for (int i = 0; i < 8; i++) base[i] = hin + (size_t)min(n0 + i, nl) * 64;
  float acc[8];
  #pragma unroll
  for (int i = 0; i < 8; i++) acc[i] = 0.f;
  #pragma unroll 2
  for (int k4 = 0; k4 < 16; k4++) {
    float w0 = Wg[(k4 * 4 + 0) * 64 + lane];
    float w1 = Wg[(k4 * 4 + 1) * 64 + lane];
    float w2 = Wg[(k4 * 4 + 2) * 64 + lane];
    float w3 = Wg[(k4 * 4 + 3) * 64 + lane];
    #pragma unroll
    for (int i = 0; i < 8; i++) {
      float4 a = *(const float4*)(base[i] + k4 * 4);
      acc[i] = fmaf(a.x, w0, acc[i]);
      acc[i] = fmaf(a.y, w1, acc[i]);
      acc[i] = fmaf(a.z, w2, acc[i]);
      acc[i] = fmaf(a.w, w3, acc[i]);
    }
  }
  float salv = al[lane], sarv = ar[lane];
  #pragma unroll
  for (int i = 0; i < 8; i++) {
    int n = n0 + i;
    if (n < N) feat[(size_t)n * 64 + lane] = acc[i];
    float rl = acc[i] * salv, rr = acc[i] * sarv;
    #pragma unroll
    for (int off = 32; off; off >>= 1) {
      rl += __shfl_xor(rl, off, 64);
      rr += __shfl_xor(rr, off, 64);
    }
    if (lane == 0 && n < N) { el[n] = rl; er[n] = rr; }
  }
}

// ---- edge softmax + aggregate: one wave per dst node, lane = feature ----
__global__ __launch_bounds__(256) void k_aggr(const float* __restrict__ feat,
                                              const float* __restrict__ el,
                                              const float* __restrict__ er,
                                              const int* __restrict__ row_ptr,
                                              const int* __restrict__ csr_src,
                                              unsigned char* __restrict__ mask,
                                              int write_mask, int use_mask,
                                              float* __restrict__ hout, int N) {
  __shared__ __align__(16) int   su[4][64];
  __shared__ __align__(16) float spl[4][64];
  int wv = (int)((blockIdx.x * blockDim.x + threadIdx.x) >> 6);
  int wave = threadIdx.x >> 6, lane = threadIdx.x & 63;
  if (wv >= N) return;
  int beg = row_ptr[wv], end = row_ptr[wv + 1];
  int deg = end - beg;
  float erv = er[wv];
  float acc0 = 0.f, acc1 = 0.f, acc2 = 0.f, acc3 = 0.f;
  if (deg <= 64) {
    int k = beg + lane;
    bool have = (lane < deg);
    int u = have ? csr_src[k] : 0;
    float sc = -INFINITY;
    if (have) {
      float e0 = el[u] + erv;
      sc = (e0 >= 0.f) ? e0 : 0.2f * e0;              // leaky_relu(0.2)
      if (use_mask && mask[k] == 0) sc = -1e9f;       // pruned
    }
    float m = sc;
    #pragma unroll
    for (int off = 32; off; off >>= 1) m = fmaxf(m, __shfl_xor(m, off, 64));
    float pl = have ? expf(sc - m) : 0.f;
    float s = pl;
    #pragma unroll
    for (int off = 32; off; off >>= 1) s += __shfl_xor(s, off, 64);
    pl *= 1.0f / fmaxf(s, 1e-9f);                     // alpha
    if (write_mask && have) mask[k] = (pl >= 0.01f) ? 1 : 0;
    su[wave][lane] = u;
    spl[wave][lane] = pl;                             // 0 for tail lanes
    int dq = (deg + 3) >> 2;
    #pragma unroll 2
    for (int q = 0; q < dq; q++) {
      int4   uu = *(const int4*)&su[wave][q * 4];     // uniform broadcast
      float4 pp = *(const float4*)&spl[wave][q * 4];
      acc0 = fmaf(pp.x, feat[(size_t)uu.x * 64 + lane], acc0);
      acc1 = fmaf(pp.y, feat[(size_t)uu.y * 64 + lane], acc1);
      acc2 = fmaf(pp.z, feat[(size_t)uu.z * 64 + lane], acc2);
      acc3 = fmaf(pp.w, feat[(size_t)uu.w * 64 + lane], acc3);
    }
  } else {
    // generic fallback (deg > 64): streaming two-pass
    float m = -INFINITY, s = 0.f;
    for (int base = beg; base < end; base += 64) {
      int k = base + lane;
      float sc = -INFINITY;
      if (k < end) {
        int u = csr_src[k];
        float e0 = el[u] + erv;
        sc = (e0 >= 0.f) ? e0 : 0.2f * e0;
        if (use_mask && mask[k] == 0) sc = -1e9f;
      }
      float cm = sc;
      #pragma unroll
      for (int off = 32; off; off >>= 1) cm = fmaxf(cm, __shfl_xor(cm, off, 64));
      float nm = fmaxf(m, cm);
      float t = (k < end) ? expf(sc - nm) : 0.f;
      #pragma unroll
      for (int off = 32; off; off >>= 1) t += __shfl_xor(t, off, 64);
      s = s * expf(m - nm) + t;
      m = nm;
    }
    float inv = 1.0f / fmaxf(s, 1e-9f);
    for (int base = beg; base < end; base += 64) {
      int k = base + lane;
      int u = 0;
      float pl = 0.f;
      if (k < end) {
        u = csr_src[k];
        float e0 = el[u] + erv;
        float sc = (e0 >= 0.f) ? e0 : 0.2f * e0;
        if (use_mask && mask[k] == 0) sc = -1e9f;
        pl = expf(sc - m) * inv;
        if (write_mask) mask[k] = (pl >= 0.01f) ? 1 : 0;
      }
      su[wave][lane] = u;
      spl[wave][lane] = pl;
      int cnt = min(64, end - base);
      int dq = (cnt + 3) >> 2;
      for (int q = 0; q < dq; q++) {
        int4   uu = *(const int4*)&su[wave][q * 4];
        float4 pp = *(const float4*)&spl[wave][q * 4];
        acc0 = fmaf(pp.x, feat[(size_t)uu.x * 64 + lane], acc0);
        acc1 = fmaf(pp.y, feat[(size_t)uu.y * 64 + lane], acc1);
        acc2 = fmaf(pp.z, feat[(size_t)uu.z * 64 + lane], acc2);
        acc3 = fmaf(pp.w, feat[(size_t)uu.w * 64 + lane], acc3);
      }
    }
  }
  float acc = (acc0 + acc1) + (acc2 + acc3);
  hout[(size_t)wv * 64 + lane] = (acc > 0.f) ? acc : expm1f(acc);  // elu
}

// ---- MLP head: weights from global (L1/L2), small per-wave LDS stage ----
__global__ __launch_bounds__(256) void k_mlp(const float* __restrict__ o0,
                                             const float* __restrict__ o1,
                                             const float* __restrict__ o2,
                                             const float* __restrict__ o3,
                                             const float* __restrict__ W0,
                                             const float* __restrict__ b0,
                                             const float* __restrict__ W1,
                                             const float* __restrict__ b1,
                                             const float* __restrict__ W2,
                                             const float* __restrict__ b2,
                                             float* __restrict__ out, int N) {
  __shared__ __align__(16) float sF[4][8 * 64];  // 8 KB inter-layer stage
  int wave = threadIdx.x >> 6, lane = threadIdx.x & 63;
  int n0 = (blockIdx.x * 4 + wave) * 8;
  if (n0 >= N) return;
  int nl = N - 1;
  float* sf = sF[wave];
  float acc[8];
  float b0v = b0[lane];
  #pragma unroll
  for (int i = 0; i < 8; i++) acc[i] = b0v;
  const float* segs[4] = {o0, o1, o2, o3};
  for (int sg = 0; sg < 4; sg++) {
    const float* sp = segs[sg];
    const float* wp = W0 + (size_t)sg * 64 * 64;
    const float* base[8];
    #pragma unroll
    for (int i = 0; i < 8; i++) base[i] = sp + (size_t)min(n0 + i, nl) * 64;
    #pragma unroll 2
    for (int k4 = 0; k4 < 16; k4++) {
      float w0 = wp[(k4 * 4 + 0) * 64 + lane];
      float w1 = wp[(k4 * 4 + 1) * 64 + lane];
      float w2 = wp[(k4 * 4 + 2) * 64 + lane];
      float w3 = wp[(k4 * 4 + 3) * 64 + lane];
      #pragma unroll
      for (int i = 0; i < 8; i++) {
        float4 a = *(const float4*)(base[i] + k4 * 4);
        acc[i] = fmaf(a.x, w0, acc[i]);
        acc[i] = fmaf(a.y, w1, acc[i]);
        acc[i] = fmaf(a.z, w2, acc[i]);
        acc[i] = fmaf(a.w, w3, acc[i]);
      }
    }
  }
  #pragma unroll
  for (int i = 0; i < 8; i++)
    sf[i * 64 + lane] = (acc[i] > 0.f) ? acc[i] : 0.f;   // relu, per-wave stage
  float a1[8];
  float b1v = b1[lane];
  #pragma unroll
  for (int i = 0; i < 8; i++) a1[i] = b1v;
  #pragma unroll 2
  for (int k4 = 0; k4 < 16; k4++) {
    float w0 = W1[(k4 * 4 + 0) * 64 + lane];
    float w1 = W1[(k4 * 4 + 1) * 64 + lane];
    float w2 = W1[(k4 * 4 + 2) * 64 + lane];
    float w3 = W1[(k4 * 4 + 3) * 64 + lane];
    #pragma unroll
    for (int i = 0; i < 8; i++) {
      float4 a = *(const float4*)&sf[i * 64 + k4 * 4];
      a1[i] = fmaf(a.x, w0, a1[i]);
      a1[i] = fmaf(a.y, w1, a1[i]);
      a1[i] = fmaf(a.z, w2, a1[i]);
      a1[i] = fmaf(a.w, w3, a1[i]);
    }
  }
  float w2v = W2[lane];
  float b2v = b2[0];
  #pragma unroll
  for (int i = 0; i < 8; i++) {
    float t = (a1[i] > 0.f) ? a1[i] : 0.f;
    float r = t * w2v;
    #pragma unroll
    for (int off = 32; off; off >>= 1) r += __shfl_xor(r, off, 64);
    int n = n0 + i;
    if (lane == 0 && n < N) {
      float o = r + b2v;
      out[n] = (o > 0.f) ? o : 0.f;
    }
  }
}

extern "C" void kernel_launch(void* const* d_in, const int* in_sizes, int n_in,
                              void* d_out, int out_size, void* d_ws, size_t ws_size,
                              hipStream_t stream) {
  const float* x       = (const float*)d_in[0];
  const int*   esrc    = (const int*)d_in[1];
  const int*   edst    = (const int*)d_in[2];
  const float* W_embed = (const float*)d_in[3];
  const float* W_gat   = (const float*)d_in[4];
  const float* a_l     = (const float*)d_in[5];
  const float* a_r     = (const float*)d_in[6];
  const float* W0      = (const float*)d_in[7];
  const float* b0      = (const float*)d_in[8];
  const float* W1      = (const float*)d_in[9];
  const float* b1      = (const float*)d_in[10];
  const float* W2      = (const float*)d_in[11];
  const float* b2      = (const float*)d_in[12];
  float* out = (float*)d_out;
  const int N = in_sizes[0] / 128;
  const int E = in_sizes[1];

  char* p = (char*)d_ws;
  auto alloc = [&](size_t bytes) -> char* {
    char* r = p;
    p += (bytes + 255) & ~(size_t)255;
    return r;
  };
  float* out0 = (float*)alloc((size_t)N * 64 * 4);
  float* out1 = (float*)alloc((size_t)N * 64 * 4);
  float* out2 = (float*)alloc((size_t)N * 64 * 4);
  float* out3 = (float*)alloc((size_t)N * 64 * 4);
  float* h    = out3;  // alias: h dead before out3 written
  float* feat = (float*)alloc((size_t)N * 64 * 4);
  float* el   = (float*)alloc((size_t)N * 4);
  float* er   = (float*)alloc((size_t)N * 4);
  int* counts  = (int*)alloc((size_t)N * 4);
  int* row_ptr = (int*)alloc((size_t)(N + 1) * 4);
  int* cursor  = (int*)alloc((size_t)N * 4);
  int* csr_src = (int*)alloc((size_t)E * 4);
  unsigned char* mask = (unsigned char*)alloc((size_t)E);
  int nb = (N + 1023) / 1024;
  int* bsum = (int*)alloc((size_t)nb * 4);
  int* bofs = (int*)alloc((size_t)nb * 4);

  // --- CSR build (dst-sorted) ---
  k_zero_i32<<<(N + 255) / 256, 256, 0, stream>>>(counts, N);
  k_hist<<<(E + 255) / 256, 256, 0, stream>>>(edst, counts, E);
  k_bsum<<<nb, 1024, 0, stream>>>(counts, bsum, N);
  k_bscan<<<1, 64, 0, stream>>>(bsum, bofs, row_ptr, nb, N);
  k_scan3<<<nb, 1024, 0, stream>>>(counts, bofs, row_ptr, cursor, N);
  k_scatter<<<(E + 255) / 256, 256, 0, stream>>>(esrc, edst, cursor, csr_src, E);

  // --- embed ---
  int groups = (N + 7) / 8;
  int gb = (groups + 3) / 4;
  k_embed<<<gb, 256, 0, stream>>>(x, W_embed, h, N);

  // --- 4 conv layers ---
  const float* hin = h;
  float* outs[4] = {out0, out1, out2, out3};
  for (int l = 0; l < 4; l++) {
    k_feat<<<gb, 256, 0, stream>>>(hin, W_gat + (size_t)l * 64 * 64,
                                   a_l + (size_t)l * 64, a_r + (size_t)l * 64,
                                   feat, el, er, N);
    k_aggr<<<(N + 3) / 4, 256, 0, stream>>>(feat, el, er, row_ptr, csr_src, mask,
                                            (l == 0) ? 1 : 0, (l > 0) ? 1 : 0,
                                            outs[l], N);
    hin = outs[l];
  }

  // --- MLP head ---
  k_mlp<<<gb, 256, 0, stream>>>(out0, out1, out2, out3, W0, b0, W1, b1,
                                W2, b2, out, N);
}

// Round 4
// 539.894 us; speedup vs baseline: 1.7925x; 1.2174x over previous
//
#include <hip/hip_runtime.h>
#include <math.h>

// ---------------------------------------------------------------------------
// SNAT3: 4-layer GAT-like GNN. N=50000, E=800000, HID=64, fp32.
// R4: dense kernels (embed/feat/mlp) keep lane=out-feature, 8 nodes/wave,
// but ALL inner-loop operands come from LDS:
//   - weights: cooperatively staged per block (stride-1 b32 reads, 2/bank=free)
//   - activations: per-wave staged rows, read as broadcast ds_read_b128
// This removes global (L2) latency from the loop body entirely; R3 was
// VMEM-latency-bound (VALUBusy 27%, 12 global loads per 64 FMA-cycles).
// ---------------------------------------------------------------------------

__global__ void k_zero_i32(int* __restrict__ p, int n) {
  int i = blockIdx.x * blockDim.x + threadIdx.x;
  if (i < n) p[i] = 0;
}

__global__ void k_hist(const int* __restrict__ dst, int* __restrict__ counts, int E) {
  int e = blockIdx.x * blockDim.x + threadIdx.x;
  if (e < E) atomicAdd(&counts[dst[e]], 1);
}

__global__ __launch_bounds__(1024) void k_bsum(const int* __restrict__ counts,
                                               int* __restrict__ bsum, int n) {
  __shared__ int wsum[16];
  int tid = threadIdx.x, lane = tid & 63, wid = tid >> 6;
  int i = blockIdx.x * 1024 + tid;
  int v = (i < n) ? counts[i] : 0;
  #pragma unroll
  for (int off = 32; off; off >>= 1) v += __shfl_xor(v, off, 64);
  if (lane == 0) wsum[wid] = v;
  __syncthreads();
  if (wid == 0) {
    int w = (lane < 16) ? wsum[lane] : 0;
    #pragma unroll
    for (int off = 8; off; off >>= 1) w += __shfl_xor(w, off, 64);
    if (lane == 0) bsum[blockIdx.x] = w;
  }
}

__global__ __launch_bounds__(64) void k_bscan(const int* __restrict__ bsum,
                                              int* __restrict__ bofs,
                                              int* __restrict__ row_ptr,
                                              int nb, int n) {
  int lane = threadIdx.x;
  int carry = 0;
  for (int base = 0; base < nb; base += 64) {
    int idx = base + lane;
    int orig = (idx < nb) ? bsum[idx] : 0;
    int inc = orig;
    #pragma unroll
    for (int off = 1; off < 64; off <<= 1) {
      int t = __shfl_up(inc, off, 64);
      if (lane >= off) inc += t;
    }
    if (idx < nb) bofs[idx] = carry + inc - orig;
    carry += __shfl(inc, 63, 64);
  }
  if (lane == 0) row_ptr[n] = carry;
}

__global__ __launch_bounds__(1024) void k_scan3(const int* __restrict__ counts,
                                                const int* __restrict__ bofs,
                                                int* __restrict__ row_ptr,
                                                int* __restrict__ cursor, int n) {
  __shared__ int wsum[16];
  int tid = threadIdx.x, lane = tid & 63, wid = tid >> 6;
  int i = blockIdx.x * 1024 + tid;
  int v = (i < n) ? counts[i] : 0;
  int inc = v;
  #pragma unroll
  for (int off = 1; off < 64; off <<= 1) {
    int t = __shfl_up(inc, off, 64);
    if (lane >= off) inc += t;
  }
  if (lane == 63) wsum[wid] = inc;
  __syncthreads();
  if (wid == 0 && lane < 16) {
    int orig = wsum[lane];
    int w = orig;
    #pragma unroll
    for (int off = 1; off < 16; off <<= 1) {
      int t = __shfl_up(w, off, 64);
      if (lane >= off) w += t;
    }
    wsum[lane] = w - orig;
  }
  __syncthreads();
  int excl = bofs[blockIdx.x] + wsum[wid] + inc - v;
  if (i < n) { row_ptr[i] = excl; cursor[i] = excl; }
}

__global__ void k_scatter(const int* __restrict__ src, const int* __restrict__ dst,
                          int* __restrict__ cursor, int* __restrict__ csr_src, int E) {
  int e = blockIdx.x * blockDim.x + threadIdx.x;
  if (e < E) {
    int pos = atomicAdd(&cursor[dst[e]], 1);
    csr_src[pos] = src[e];
  }
}

// ---- h = tanh(x @ W_embed)   x:[N,128] W:[128,64] ----
__global__ __launch_bounds__(256) void k_embed(const float* __restrict__ x,
                                               const float* __restrict__ W,
                                               float* __restrict__ h, int N) {
  __shared__ __align__(16) float sW[128 * 64];     // 32 KB
  __shared__ __align__(16) float sA[4][8 * 128];   // 16 KB
  for (int i = threadIdx.x; i < 128 * 64; i += 256) sW[i] = W[i];
  int wave = threadIdx.x >> 6, lane = threadIdx.x & 63;
  int n0 = (blockIdx.x * 4 + wave) * 8;
  int nl = N - 1;
  float* sf = sA[wave];
  if (n0 < N) {
    #pragma unroll
    for (int i = 0; i < 8; i++) {
      const float* xp = x + (size_t)min(n0 + i, nl) * 128;
      ((float2*)sf)[i * 64 + lane] = ((const float2*)xp)[lane];
    }
  }
  __syncthreads();
  if (n0 >= N) return;
  float acc[8];
  #pragma unroll
  for (int i = 0; i < 8; i++) acc[i] = 0.f;
  #pragma unroll 2
  for (int k4 = 0; k4 < 32; k4++) {
    float w0 = sW[(k4 * 4 + 0) * 64 + lane];
    float w1 = sW[(k4 * 4 + 1) * 64 + lane];
    float w2 = sW[(k4 * 4 + 2) * 64 + lane];
    float w3 = sW[(k4 * 4 + 3) * 64 + lane];
    #pragma unroll
    for (int i = 0; i < 8; i++) {
      float4 a = *(const float4*)&sf[i * 128 + k4 * 4];  // broadcast
      acc[i] = fmaf(a.x, w0, acc[i]);
      acc[i] = fmaf(a.y, w1, acc[i]);
      acc[i] = fmaf(a.z, w2, acc[i]);
      acc[i] = fmaf(a.w, w3, acc[i]);
    }
  }
  #pragma unroll
  for (int i = 0; i < 8; i++)
    if (n0 + i < N) h[(size_t)(n0 + i) * 64 + lane] = tanhf(acc[i]);
}

// ---- feat = hin @ Wg; el/er dot products ----
__global__ __launch_bounds__(256) void k_feat(const float* __restrict__ hin,
                                              const float* __restrict__ Wg,
                                              const float* __restrict__ al,
                                              const float* __restrict__ ar,
                                              float* __restrict__ feat,
                                              float* __restrict__ el,
                                              float* __restrict__ er, int N) {
  __shared__ __align__(16) float sW[64 * 64];      // 16 KB
  __shared__ __align__(16) float sA[4][8 * 64];    // 8 KB
  for (int i = threadIdx.x; i < 64 * 64; i += 256) sW[i] = Wg[i];
  int wave = threadIdx.x >> 6, lane = threadIdx.x & 63;
  int n0 = (blockIdx.x * 4 + wave) * 8;
  int nl = N - 1;
  float* sf = sA[wave];
  if (n0 < N) {
    #pragma unroll
    for (int i = 0; i < 8; i++)
      sf[i * 64 + lane] = hin[(size_t)min(n0 + i, nl) * 64 + lane];
  }
  __syncthreads();
  if (n0 >= N) return;
  float acc[8];
  #pragma unroll
  for (int i = 0; i < 8; i++) acc[i] = 0.f;
  #pragma unroll 2
  for (int k4 = 0; k4 < 16; k4++) {
    float w0 = sW[(k4 * 4 + 0) * 64 + lane];
    float w1 = sW[(k4 * 4 + 1) * 64 + lane];
    float w2 = sW[(k4 * 4 + 2) * 64 + lane];
    float w3 = sW[(k4 * 4 + 3) * 64 + lane];
    #pragma unroll
    for (int i = 0; i < 8; i++) {
      float4 a = *(const float4*)&sf[i * 64 + k4 * 4];
      acc[i] = fmaf(a.x, w0, acc[i]);
      acc[i] = fmaf(a.y, w1, acc[i]);
      acc[i] = fmaf(a.z, w2, acc[i]);
      acc[i] = fmaf(a.w, w3, acc[i]);
    }
  }
  float salv = al[lane], sarv = ar[lane];
  #pragma unroll
  for (int i = 0; i < 8; i++) {
    int n = n0 + i;
    if (n < N) feat[(size_t)n * 64 + lane] = acc[i];
    float rl = acc[i] * salv, rr = acc[i] * sarv;
    #pragma unroll
    for (int off = 32; off; off >>= 1) {
      rl += __shfl_xor(rl, off, 64);
      rr += __shfl_xor(rr, off, 64);
    }
    if (lane == 0 && n < N) { el[n] = rl; er[n] = rr; }
  }
}

// ---- edge softmax + aggregate: one wave per dst node, lane = feature ----
__global__ __launch_bounds__(256) void k_aggr(const float* __restrict__ feat,
                                              const float* __restrict__ el,
                                              const float* __restrict__ er,
                                              const int* __restrict__ row_ptr,
                                              const int* __restrict__ csr_src,
                                              unsigned char* __restrict__ mask,
                                              int write_mask, int use_mask,
                                              float* __restrict__ hout, int N) {
  __shared__ __align__(16) int   su[4][64];
  __shared__ __align__(16) float spl[4][64];
  int wv = (int)((blockIdx.x * blockDim.x + threadIdx.x) >> 6);
  int wave = threadIdx.x >> 6, lane = threadIdx.x & 63;
  if (wv >= N) return;
  int beg = row_ptr[wv], end = row_ptr[wv + 1];
  int deg = end - beg;
  float erv = er[wv];
  float acc0 = 0.f, acc1 = 0.f, acc2 = 0.f, acc3 = 0.f;
  if (deg <= 64) {
    int k = beg + lane;
    bool have = (lane < deg);
    int u = have ? csr_src[k] : 0;
    float sc = -INFINITY;
    if (have) {
      float e0 = el[u] + erv;
      sc = (e0 >= 0.f) ? e0 : 0.2f * e0;              // leaky_relu(0.2)
      if (use_mask && mask[k] == 0) sc = -1e9f;       // pruned
    }
    float m = sc;
    #pragma unroll
    for (int off = 32; off; off >>= 1) m = fmaxf(m, __shfl_xor(m, off, 64));
    float pl = have ? expf(sc - m) : 0.f;
    float s = pl;
    #pragma unroll
    for (int off = 32; off; off >>= 1) s += __shfl_xor(s, off, 64);
    pl *= 1.0f / fmaxf(s, 1e-9f);                     // alpha
    if (write_mask && have) mask[k] = (pl >= 0.01f) ? 1 : 0;
    su[wave][lane] = u;
    spl[wave][lane] = pl;                             // 0 for tail lanes
    int dq = (deg + 3) >> 2;
    #pragma unroll 2
    for (int q = 0; q < dq; q++) {
      int4   uu = *(const int4*)&su[wave][q * 4];     // uniform broadcast
      float4 pp = *(const float4*)&spl[wave][q * 4];
      acc0 = fmaf(pp.x, feat[(size_t)uu.x * 64 + lane], acc0);
      acc1 = fmaf(pp.y, feat[(size_t)uu.y * 64 + lane], acc1);
      acc2 = fmaf(pp.z, feat[(size_t)uu.z * 64 + lane], acc2);
      acc3 = fmaf(pp.w, feat[(size_t)uu.w * 64 + lane], acc3);
    }
  } else {
    // generic fallback (deg > 64): streaming two-pass
    float m = -INFINITY, s = 0.f;
    for (int base = beg; base < end; base += 64) {
      int k = base + lane;
      float sc = -INFINITY;
      if (k < end) {
        int u = csr_src[k];
        float e0 = el[u] + erv;
        sc = (e0 >= 0.f) ? e0 : 0.2f * e0;
        if (use_mask && mask[k] == 0) sc = -1e9f;
      }
      float cm = sc;
      #pragma unroll
      for (int off = 32; off; off >>= 1) cm = fmaxf(cm, __shfl_xor(cm, off, 64));
      float nm = fmaxf(m, cm);
      float t = (k < end) ? expf(sc - nm) : 0.f;
      #pragma unroll
      for (int off = 32; off; off >>= 1) t += __shfl_xor(t, off, 64);
      s = s * expf(m - nm) + t;
      m = nm;
    }
    float inv = 1.0f / fmaxf(s, 1e-9f);
    for (int base = beg; base < end; base += 64) {
      int k = base + lane;
      int u = 0;
      float pl = 0.f;
      if (k < end) {
        u = csr_src[k];
        float e0 = el[u] + erv;
        float sc = (e0 >= 0.f) ? e0 : 0.2f * e0;
        if (use_mask && mask[k] == 0) sc = -1e9f;
        pl = expf(sc - m) * inv;
        if (write_mask) mask[k] = (pl >= 0.01f) ? 1 : 0;
      }
      su[wave][lane] = u;
      spl[wave][lane] = pl;
      int cnt = min(64, end - base);
      int dq = (cnt + 3) >> 2;
      for (int q = 0; q < dq; q++) {
        int4   uu = *(const int4*)&su[wave][q * 4];
        float4 pp = *(const float4*)&spl[wave][q * 4];
        acc0 = fmaf(pp.x, feat[(size_t)uu.x * 64 + lane], acc0);
        acc1 = fmaf(pp.y, feat[(size_t)uu.y * 64 + lane], acc1);
        acc2 = fmaf(pp.z, feat[(size_t)uu.z * 64 + lane], acc2);
        acc3 = fmaf(pp.w, feat[(size_t)uu.w * 64 + lane], acc3);
      }
    }
  }
  float acc = (acc0 + acc1) + (acc2 + acc3);
  hout[(size_t)wv * 64 + lane] = (acc > 0.f) ? acc : expm1f(acc);  // elu
}

// ---- MLP head: W0 staged seg-by-seg, W1 staged once, acts per-wave ----
__global__ __launch_bounds__(256) void k_mlp(const float* __restrict__ o0,
                                             const float* __restrict__ o1,
                                             const float* __restrict__ o2,
                                             const float* __restrict__ o3,
                                             const float* __restrict__ W0,
                                             const float* __restrict__ b0,
                                             const float* __restrict__ W1,
                                             const float* __restrict__ b1,
                                             const float* __restrict__ W2,
                                             const float* __restrict__ b2,
                                             float* __restrict__ out, int N) {
  __shared__ __align__(16) float sW[64 * 64];      // 16 KB rotating W0 seg
  __shared__ __align__(16) float sW1[64 * 64];     // 16 KB W1
  __shared__ __align__(16) float sA[4][8 * 64];    // 8 KB per-wave acts
  for (int i = threadIdx.x; i < 64 * 64; i += 256) sW1[i] = W1[i];
  int wave = threadIdx.x >> 6, lane = threadIdx.x & 63;
  int n0 = (blockIdx.x * 4 + wave) * 8;
  int nl = N - 1;
  float* sf = sA[wave];
  float acc[8];
  float b0v = b0[lane];
  #pragma unroll
  for (int i = 0; i < 8; i++) acc[i] = b0v;
  const float* segs[4] = {o0, o1, o2, o3};
  for (int sg = 0; sg < 4; sg++) {
    __syncthreads();  // previous seg reads done (also orders sW1 store/use)
    for (int i = threadIdx.x; i < 64 * 64; i += 256) sW[i] = W0[sg * 4096 + i];
    if (n0 < N) {
      const float* sp = segs[sg];
      #pragma unroll
      for (int i = 0; i < 8; i++)
        sf[i * 64 + lane] = sp[(size_t)min(n0 + i, nl) * 64 + lane];
    }
    __syncthreads();
    if (n0 < N) {
      #pragma unroll 2
      for (int k4 = 0; k4 < 16; k4++) {
        float w0 = sW[(k4 * 4 + 0) * 64 + lane];
        float w1 = sW[(k4 * 4 + 1) * 64 + lane];
        float w2 = sW[(k4 * 4 + 2) * 64 + lane];
        float w3 = sW[(k4 * 4 + 3) * 64 + lane];
        #pragma unroll
        for (int i = 0; i < 8; i++) {
          float4 a = *(const float4*)&sf[i * 64 + k4 * 4];
          acc[i] = fmaf(a.x, w0, acc[i]);
          acc[i] = fmaf(a.y, w1, acc[i]);
          acc[i] = fmaf(a.z, w2, acc[i]);
          acc[i] = fmaf(a.w, w3, acc[i]);
        }
      }
    }
  }
  if (n0 >= N) return;
  #pragma unroll
  for (int i = 0; i < 8; i++)
    sf[i * 64 + lane] = (acc[i] > 0.f) ? acc[i] : 0.f;   // relu -> own region
  float a1[8];
  float b1v = b1[lane];
  #pragma unroll
  for (int i = 0; i < 8; i++) a1[i] = b1v;
  #pragma unroll 2
  for (int k4 = 0; k4 < 16; k4++) {
    float w0 = sW1[(k4 * 4 + 0) * 64 + lane];
    float w1 = sW1[(k4 * 4 + 1) * 64 + lane];
    float w2 = sW1[(k4 * 4 + 2) * 64 + lane];
    float w3 = sW1[(k4 * 4 + 3) * 64 + lane];
    #pragma unroll
    for (int i = 0; i < 8; i++) {
      float4 a = *(const float4*)&sf[i * 64 + k4 * 4];
      a1[i] = fmaf(a.x, w0, a1[i]);
      a1[i] = fmaf(a.y, w1, a1[i]);
      a1[i] = fmaf(a.z, w2, a1[i]);
      a1[i] = fmaf(a.w, w3, a1[i]);
    }
  }
  float w2v = W2[lane];
  float b2v = b2[0];
  #pragma unroll
  for (int i = 0; i < 8; i++) {
    float t = (a1[i] > 0.f) ? a1[i] : 0.f;
    float r = t * w2v;
    #pragma unroll
    for (int off = 32; off; off >>= 1) r += __shfl_xor(r, off, 64);
    int n = n0 + i;
    if (lane == 0 && n < N) {
      float o = r + b2v;
      out[n] = (o > 0.f) ? o : 0.f;
    }
  }
}

extern "C" void kernel_launch(void* const* d_in, const int* in_sizes, int n_in,
                              void* d_out, int out_size, void* d_ws, size_t ws_size,
                              hipStream_t stream) {
  const float* x       = (const float*)d_in[0];
  const int*   esrc    = (const int*)d_in[1];
  const int*   edst    = (const int*)d_in[2];
  const float* W_embed = (const float*)d_in[3];
  const float* W_gat   = (const float*)d_in[4];
  const float* a_l     = (const float*)d_in[5];
  const float* a_r     = (const float*)d_in[6];
  const float* W0      = (const float*)d_in[7];
  const float* b0      = (const float*)d_in[8];
  const float* W1      = (const float*)d_in[9];
  const float* b1      = (const float*)d_in[10];
  const float* W2      = (const float*)d_in[11];
  const float* b2      = (const float*)d_in[12];
  float* out = (float*)d_out;
  const int N = in_sizes[0] / 128;
  const int E = in_sizes[1];

  char* p = (char*)d_ws;
  auto alloc = [&](size_t bytes) -> char* {
    char* r = p;
    p += (bytes + 255) & ~(size_t)255;
    return r;
  };
  float* out0 = (float*)alloc((size_t)N * 64 * 4);
  float* out1 = (float*)alloc((size_t)N * 64 * 4);
  float* out2 = (float*)alloc((size_t)N * 64 * 4);
  float* out3 = (float*)alloc((size_t)N * 64 * 4);
  float* h    = out3;  // alias: h dead before out3 written
  float* feat = (float*)alloc((size_t)N * 64 * 4);
  float* el   = (float*)alloc((size_t)N * 4);
  float* er   = (float*)alloc((size_t)N * 4);
  int* counts  = (int*)alloc((size_t)N * 4);
  int* row_ptr = (int*)alloc((size_t)(N + 1) * 4);
  int* cursor  = (int*)alloc((size_t)N * 4);
  int* csr_src = (int*)alloc((size_t)E * 4);
  unsigned char* mask = (unsigned char*)alloc((size_t)E);
  int nb = (N + 1023) / 1024;
  int* bsum = (int*)alloc((size_t)nb * 4);
  int* bofs = (int*)alloc((size_t)nb * 4);

  // --- CSR build (dst-sorted) ---
  k_zero_i32<<<(N + 255) / 256, 256, 0, stream>>>(counts, N);
  k_hist<<<(E + 255) / 256, 256, 0, stream>>>(edst, counts, E);
  k_bsum<<<nb, 1024, 0, stream>>>(counts, bsum, N);
  k_bscan<<<1, 64, 0, stream>>>(bsum, bofs, row_ptr, nb, N);
  k_scan3<<<nb, 1024, 0, stream>>>(counts, bofs, row_ptr, cursor, N);
  k_scatter<<<(E + 255) / 256, 256, 0, stream>>>(esrc, edst, cursor, csr_src, E);

  // --- embed ---
  int groups = (N + 7) / 8;
  int gb = (groups + 3) / 4;
  k_embed<<<gb, 256, 0, stream>>>(x, W_embed, h, N);

  // --- 4 conv layers ---
  const float* hin = h;
  float* outs[4] = {out0, out1, out2, out3};
  for (int l = 0; l < 4; l++) {
    k_feat<<<gb, 256, 0, stream>>>(hin, W_gat + (size_t)l * 64 * 64,
                                   a_l + (size_t)l * 64, a_r + (size_t)l * 64,
                                   feat, el, er, N);
    k_aggr<<<(N + 3) / 4, 256, 0, stream>>>(feat, el, er, row_ptr, csr_src, mask,
                                            (l == 0) ? 1 : 0, (l > 0) ? 1 : 0,
                                            outs[l], N);
    hin = outs[l];
  }

  // --- MLP head ---
  k_mlp<<<gb, 256, 0, stream>>>(out0, out1, out2, out3, W0, b0, W1, b1,
                                W2, b2, out, N);
}